// Round 3
// baseline (231.906 us; speedup 1.0000x reference)
//
#include <hip/hip_runtime.h>
#include <stdint.h>

/* AdditiveAttention (B=4, Q=256, K=1024, D=512, H=256)
 * out[b,i,v] = sum_j softmax_j(sum_h tanh(q[b,i,h]+k[b,j,h])*wv[h]) * values[b,j,v],
 * masked to j < valid_lens[b].  OUTPUT IS FLOAT32 (R20 finding).
 *
 * R23: (a) ff_proj x-operand moved to LDS broadcast reads. R22's wave-uniform
 * global x loads scalarized to s_load chains; SGPR pressure serialized them
 * on ~200cy SMEM latency (proj ~100us for 8.5us of FMA). LDS broadcast
 * ds_read has no such hazard. (b) ff_attn QROWS 4->2: grid 256->512 blocks,
 * 2 blocks/CU -> 32 waves/CU (was 1 block/CU = the occupancy ceiling,
 * VALUBusy 57%). LDS/block ~27KB so 2 fit. Trade: kp+values L2 demand
 * doubles (~1.5GB, ~44us of overlappable L2 BW) for full latency hiding. */

#define NB 4
#define NQ 256
#define NK 1024
#define ND 512
#define NH 256
#define PR 8

#define C2L2E 2.8853900817779268f   /* 2*log2(e) */
#define L2E   1.4426950408889634f   /* log2(e)   */

/* 8-class valid_lens decode: {i32,i64,f32,f64,i16,f16,bf16,fallback}. */
__device__ void ff_vldec(const int* p, int* v) {
  bool ok = true;
  for (int i = 0; i < 4; ++i) { int x = p[i]; if (x < 1 || x > NK) ok = false; }
  if (ok) { for (int i = 0; i < 4; ++i) v[i] = p[i]; return; }
  ok = true;
  for (int i = 0; i < 4; ++i) {
    if (p[2 * i + 1] != 0) ok = false;
    int x = p[2 * i]; if (x < 1 || x > NK) ok = false;
  }
  if (ok) { for (int i = 0; i < 4; ++i) v[i] = p[2 * i]; return; }
  ok = true;
  for (int i = 0; i < 4; ++i) {
    union { int i; float f; } u; u.i = p[i];
    if (!(u.f >= 1.0f && u.f <= 1024.0f && u.f == floorf(u.f))) ok = false;
  }
  if (ok) {
    for (int i = 0; i < 4; ++i) { union { int i; float f; } u; u.i = p[i]; v[i] = (int)u.f; }
    return;
  }
  ok = true;
  for (int i = 0; i < 4; ++i) {
    union { long long l; double d; } u;
    u.l = ((long long)p[2 * i + 1] << 32) | (unsigned int)p[2 * i];
    if (!(u.d >= 1.0 && u.d <= 1024.0 && u.d == floor(u.d))) ok = false;
  }
  if (ok) {
    for (int i = 0; i < 4; ++i) {
      union { long long l; double d; } u;
      u.l = ((long long)p[2 * i + 1] << 32) | (unsigned int)p[2 * i];
      v[i] = (int)u.d;
    }
    return;
  }
  const uint16_t* hh = (const uint16_t*)p;
  const short*    s  = (const short*)p;
  ok = true;
  for (int i = 0; i < 4; ++i) { int x = s[i]; if (x < 1 || x > NK) ok = false; }
  if (ok) { for (int i = 0; i < 4; ++i) v[i] = s[i]; return; }
  ok = true;
  for (int i = 0; i < 4; ++i) {
    union { uint16_t u; _Float16 h; } u; u.u = hh[i];
    float f = (float)u.h;
    if (!(f >= 1.0f && f <= 1024.0f && f == floorf(f))) ok = false;
  }
  if (ok) {
    for (int i = 0; i < 4; ++i) {
      union { uint16_t u; _Float16 h; } u; u.u = hh[i];
      v[i] = (int)(float)u.h;
    }
    return;
  }
  ok = true;
  for (int i = 0; i < 4; ++i) {
    union { uint32_t u; float f; } u; u.u = ((uint32_t)hh[i]) << 16;
    if (!(u.f >= 1.0f && u.f <= 1028.0f)) ok = false;
  }
  if (ok) {
    for (int i = 0; i < 4; ++i) {
      union { uint32_t u; float f; } u; u.u = ((uint32_t)hh[i]) << 16;
      int x = (int)(u.f + 0.5f); if (x > NK) x = NK; v[i] = x;
    }
    return;
  }
  for (int i = 0; i < 4; ++i) v[i] = NK;  /* fail-safe: unmasked */
}

/* Transpose W[h][d] -> WT float4 #(d4*NH+h) = C2L2E * W[h][4d4..4d4+3]. */
__global__ __launch_bounds__(256) void ff_wt(
    const float* __restrict__ Wq, const float* __restrict__ Wk,
    float* __restrict__ WTq, float* __restrict__ WTk)
{
  const int idx = blockIdx.x * 256 + threadIdx.x;   /* 0..32767 */
  const int d4 = idx & 127, h = idx >> 7;
  const float* src = blockIdx.y ? Wk : Wq;
  float*       dst = blockIdx.y ? WTk : WTq;
  float4 w = *(const float4*)(src + (size_t)h * ND + d4 * 4);
  w.x *= C2L2E; w.y *= C2L2E; w.z *= C2L2E; w.w *= C2L2E;
  *(float4*)(dst + ((size_t)d4 * NH + h) * 4) = w;
}

/* Merged projection: blocks [0,128) -> queries (qp[r][h]), [128,640) -> keys
 * (kp[b][h][k], transposed store). Thread owns h=t for PR=8 rows. W read
 * coalesced float4 from WT; x rows staged in LDS, broadcast ds_read (R23:
 * replaces the s_load-serialized uniform global loads). */
__global__ __launch_bounds__(256) void ff_proj(
    const float* __restrict__ q_in, const float* __restrict__ k_in,
    const float* __restrict__ WTq, const float* __restrict__ WTk,
    float* __restrict__ qp, float* __restrict__ kp)
{
  __shared__ float xs[PR * ND];                  /* 16 KB */
  const int t = threadIdx.x;
  const bool isq = blockIdx.x < (NB * NQ / PR);
  const int g = isq ? blockIdx.x : (blockIdx.x - NB * NQ / PR);
  const float* xin = (isq ? q_in : k_in) + (size_t)g * PR * ND;
  const float* WT  = isq ? WTq : WTk;

  #pragma unroll
  for (int i = 0; i < 4; ++i)
    ((float4*)xs)[t + 256 * i] = ((const float4*)xin)[t + 256 * i];
  __syncthreads();

  float acc[PR];
  #pragma unroll
  for (int r = 0; r < PR; ++r) acc[r] = 0.f;

  #pragma unroll 2
  for (int d4 = 0; d4 < ND / 4; ++d4) {
    float4 w = *(const float4*)(WT + ((size_t)d4 * NH + t) * 4);
    #pragma unroll
    for (int r = 0; r < PR; ++r) {
      float4 x = *(const float4*)&xs[r * ND + d4 * 4];
      acc[r] += w.x * x.x + w.y * x.y + w.z * x.z + w.w * x.w;
    }
  }

  if (isq) {
    float* o = qp + (size_t)g * PR * NH + t;
    #pragma unroll
    for (int r = 0; r < PR; ++r) o[(size_t)r * NH] = acc[r];
  } else {
    const int r0 = g * PR;
    const int bb = r0 >> 10, rk = r0 & (NK - 1);
    float* o = kp + ((size_t)bb * NH + t) * NK + rk;
    *(float4*)o       = make_float4(acc[0], acc[1], acc[2], acc[3]);
    *(float4*)(o + 4) = make_float4(acc[4], acc[5], acc[6], acc[7]);
  }
}

/* Fused scores + masked softmax + PV.  1024 threads, QROWS=2 q-rows/block,
 * grid (128,4) = 512 blocks -> 2 blocks/CU, 32 waves/CU.
 * Phase1: thread owns k=t; score' = sum_h (-2*wv_h)/(1+exp2(q'+k')).
 * Phase2: 8 waves/row softmax. Phase3: split-k PV + LDS reduce. F32 out. */
__global__ __launch_bounds__(1024) void ff_attn(
    const float* __restrict__ qp, const float* __restrict__ kp,
    const float* __restrict__ vals, const int* __restrict__ vlraw,
    const float* __restrict__ wvp, float* __restrict__ out)
{
  __shared__ float qs[NH * 2];            /* [h][row], pre-scaled      2 KB */
  __shared__ float ws[NH];                /* -2*wv                     1 KB */
  __shared__ float st[NK * 2];            /* [k][row] scores->probs    8 KB */
  __shared__ float pm[16], psm[16];
  __shared__ float part[4 * 2 * ND];      /* split-k partials         16 KB */

  const int t  = threadIdx.x;
  const int q0 = blockIdx.x * 2;
  const int b  = blockIdx.y;

  if (t < 2 * NH) {
    const float* qsrc = qp + ((size_t)b * NQ + q0) * NH;
    const int row = t >> 8, h = t & 255;
    qs[h * 2 + row] = qsrc[t];            /* qsrc[row*NH+h] == qsrc[t] */
  }
  if (t < NH) ws[t] = -2.0f * wvp[t];
  __syncthreads();

  int vls[4];
  ff_vldec(vlraw, vls);
  const int vl = vls[b];

  /* ---- phase 1: scores, thread owns k = t ---- */
  float a0 = 0.f, a1 = 0.f;
  {
    const float* kvp = kp + (size_t)b * NH * NK + t;
    #pragma unroll 8
    for (int h = 0; h < NH; ++h) {
      float  kv = kvp[(size_t)h * NK];
      float2 q2 = *(const float2*)(qs + h * 2);
      float  w  = ws[h];
      a0 += w * __builtin_amdgcn_rcpf(1.0f + __builtin_amdgcn_exp2f(q2.x + kv));
      a1 += w * __builtin_amdgcn_rcpf(1.0f + __builtin_amdgcn_exp2f(q2.y + kv));
    }
  }
  {
    const bool okm = (t < vl);
    *(float2*)&st[t * 2] = make_float2(okm ? a0 : -1e6f, okm ? a1 : -1e6f);
  }
  __syncthreads();

  /* ---- phase 2: masked softmax, 8 waves per row ---- */
  {
    const int wid = t >> 6, lane = t & 63;
    const int row = wid >> 3, seg = wid & 7;
    const int kb = seg * 128 + lane;
    float v0 = st[(kb     ) * 2 + row];
    float v1 = st[(kb + 64) * 2 + row];
    float m = fmaxf(v0, v1);
    for (int o = 32; o; o >>= 1) m = fmaxf(m, __shfl_xor(m, o));
    if (lane == 0) pm[wid] = m;
    __syncthreads();
    {
      const float* pr = &pm[row * 8];
      m = fmaxf(fmaxf(fmaxf(pr[0], pr[1]), fmaxf(pr[2], pr[3])),
                fmaxf(fmaxf(pr[4], pr[5]), fmaxf(pr[6], pr[7])));
    }
    float e0 = __builtin_amdgcn_exp2f((v0 - m) * L2E);
    float e1 = __builtin_amdgcn_exp2f((v1 - m) * L2E);
    float sm = e0 + e1;
    for (int o = 32; o; o >>= 1) sm += __shfl_xor(sm, o);
    if (lane == 0) psm[wid] = sm;
    __syncthreads();
    float S;
    {
      const float* pr = &psm[row * 8];
      S = ((pr[0] + pr[1]) + (pr[2] + pr[3])) + ((pr[4] + pr[5]) + (pr[6] + pr[7]));
    }
    const float rr = 1.0f / S;
    st[(kb     ) * 2 + row] = e0 * rr;
    st[(kb + 64) * 2 + row] = e1 * rr;
  }
  __syncthreads();

  /* ---- phase 3: PV, split-k quarters; st[2k] b64 gives both rows ---- */
  {
    const int kq = t >> 8, c2 = (t & 255) * 2;
    const float* vb = vals + (size_t)b * NK * ND + c2;
    float ox0 = 0.f, oy0 = 0.f, ox1 = 0.f, oy1 = 0.f;
    const int k0 = kq * 256;
    #pragma unroll 8
    for (int k = k0; k < k0 + 256; ++k) {
      float2 v2 = *(const float2*)(vb + (size_t)k * ND);
      float2 pr = *(const float2*)&st[k * 2];
      ox0 += pr.x * v2.x; oy0 += pr.x * v2.y;
      ox1 += pr.y * v2.x; oy1 += pr.y * v2.y;
    }
    float* pp = &part[(size_t)kq * 2 * ND + c2];
    *(float2*)(pp     ) = make_float2(ox0, oy0);
    *(float2*)(pp + ND) = make_float2(ox1, oy1);
  }
  __syncthreads();
  {
    const int r = t >> 9, c = t & 511;
    const float* pp = &part[(size_t)r * ND + c];
    float s = 0.f;
    #pragma unroll
    for (int kq = 0; kq < 4; ++kq) s += pp[(size_t)kq * 2 * ND];
    out[((size_t)b * NQ + q0 + r) * ND + c] = s;
  }
}

extern "C" void kernel_launch(void* const* d_in, const int* in_sizes, int n_in,
                              void* d_out, int out_size, void* d_ws, size_t ws_size,
                              hipStream_t stream) {
  const float* queries = (const float*)d_in[0];
  const float* keys    = (const float*)d_in[1];
  const float* values  = (const float*)d_in[2];
  const int*   vlens   = (const int*)d_in[3];
  const float* Wq      = (const float*)d_in[4];
  const float* Wk      = (const float*)d_in[5];
  const float* wv      = (const float*)d_in[6];
  float* out = (float*)d_out;               /* F32 OUTPUT */

  float* qp  = (float*)d_ws;                /* [B][Q][H]   1 MB, pre-scaled */
  float* kp  = qp  + (size_t)NB * NQ * NH;  /* [B][H][K]   4 MB, pre-scaled */
  float* wtq = kp  + (size_t)NB * NH * NK;  /* [D/4][H]x4  512 KB */
  float* wtk = wtq + (size_t)(ND / 4) * NH * 4; /*         512 KB */

  ff_wt  <<<dim3(128, 2), 256, 0, stream>>>(Wq, Wk, wtq, wtk);
  ff_proj<<<dim3(NB * NQ / PR + NB * NK / PR), 256, 0, stream>>>(
      queries, keys, wtq, wtk, qp, kp);
  ff_attn<<<dim3(NQ / 2, NB), 1024, 0, stream>>>(qp, kp, values, vlens, wv, out);
}